// Round 17
// baseline (108.269 us; speedup 1.0000x reference)
//
#include <hip/hip_runtime.h>
#include <hip/hip_bf16.h>
#include <cstdint>
#include <cstddef>

// IR-Net binary conv 3x3 s1 p1 + BN(inference) + hardtanh, B=32 Cin=Cout=256 H=W=56.
// Ternary operands -> EXACT int8 MFMA implicit GEMM (mfma_i32_16x16x64_i8).
// R17 = R16 (z-merge, barrier-free taps, af confined per-z, per-kb bf, fused prep)
//   with X LDS shrunk to ONE 32KB cin-half + palindrome half order (0,1,1,0 via
//   g = z*18 + (c0i^z)*9 + tap) -> only 2 restages, and LDS 32KB + VGPR<=128
//   gives 4 blocks/CU (4 waves/SIMD): real TLP to hide the per-step af L2 latency
//   (R16's occupancy 14.5% ~ 1.2 waves/SIMD was the measured residual stall).

typedef int int4v __attribute__((ext_vector_type(4)));

#define CIN   256
#define COUT  256
#define SPAT  3136   // 56*56
#define SPAD  3364   // 58*58 padded spatial
#define BATCH 32
#define XHALF 32768  // 256 rows x 128 B

// ---------------- fused prep: pack X (sign->i8, padded), halo clear, W prep ----------------
__global__ __launch_bounds__(256) void prep_kernel(
    const float* __restrict__ x, int8_t* __restrict__ xp,
    const float* __restrict__ wgt, const float* __restrict__ gamma,
    const float* __restrict__ beta, const float* __restrict__ rmean,
    const float* __restrict__ rvar, int8_t* __restrict__ wfrag,
    float* __restrict__ Sc, float* __restrict__ Tc) {
  const int bx  = blockIdx.x;
  const int by  = blockIdx.y;
  const int tid = threadIdx.x;

  if (bx < 49) {                         // ---- pack: 64 px x 256 cin for image by
    const int s0 = bx * 64;
    __shared__ uint8_t xt[64][272];      // 64 px x 256 cin bytes (+16 pad)
    const int g  = tid >> 6;             // cin quarter 0..3
    const int si = tid & 63;             // px within chunk
#pragma unroll
    for (int k = 0; k < 4; ++k) {        // 16 cin per iter -> one 16B LDS store
      const int cin16 = (g * 4 + k) * 16;
      const float* src = x + ((size_t)by * CIN + cin16) * SPAT + s0 + si;
      uint32_t w[4] = {0u, 0u, 0u, 0u};
#pragma unroll
      for (int e = 0; e < 16; ++e) {
        float v = src[(size_t)e * SPAT];
        uint32_t sb = (v > 0.f) ? 1u : ((v < 0.f) ? 0xFFu : 0u);
        w[e >> 2] |= sb << ((e & 3) * 8);
      }
      *(int4v*)&xt[si][cin16] = (int4v){(int)w[0], (int)w[1], (int)w[2], (int)w[3]};
    }
    __syncthreads();
    const int row = tid >> 2;            // px 0..63
    const int sub = tid & 3;             // 64-cin quarter
    const int s = s0 + row;
    const int h = s / 56;
    int8_t* dst = xp + ((size_t)by * SPAD + (size_t)(s + 2 * h + 59)) * CIN + sub * 64;
#pragma unroll
    for (int j = 0; j < 4; ++j)
      *(int4v*)(dst + j * 16) = *(const int4v*)&xt[row][sub * 64 + j * 16];
    return;
  }

  if (bx == 49) {                        // ---- halo: zero 228 pad pixels of image by
    int8_t* xpb = xp + (size_t)by * SPAD * CIN;
    const int4v zz = (int4v){0, 0, 0, 0};
    for (int q = tid; q < 228 * 16; q += 256) {
      int p = q >> 4, c = q & 15;
      int pp;
      if (p < 58)       pp = p;                      // top row 0
      else if (p < 116) pp = 57 * 58 + (p - 58);     // bottom row 57
      else if (p < 172) pp = (p - 116 + 1) * 58;     // left col, rows 1..56
      else              pp = (p - 172 + 1) * 58 + 57;// right col, rows 1..56
      *(int4v*)(xpb + (size_t)pp * CIN + c * 16) = zz;
    }
    return;
  }

  // ---- W prep: co = (bx-50)*32 + by, one cout channel per block
  const int co = (bx - 50) * 32 + by;
  __shared__ float red[256];
  const float* wc = wgt + (size_t)co * 2304;
  float v[9];
#pragma unroll
  for (int j = 0; j < 9; ++j) v[j] = wc[tid + j * 256];
  float s = 0.f;
#pragma unroll
  for (int j = 0; j < 9; ++j) s += v[j];
  red[tid] = s; __syncthreads();
#pragma unroll
  for (int o = 128; o > 0; o >>= 1) { if (tid < o) red[tid] += red[tid + o]; __syncthreads(); }
  const float mean = red[0] * (1.0f / 2304.0f);
  __syncthreads();
  float ss = 0.f, sa = 0.f;
#pragma unroll
  for (int j = 0; j < 9; ++j) {
    float d = v[j] - mean;
    ss += d * d;
    sa += fabsf(d);
  }
  red[tid] = ss; __syncthreads();
#pragma unroll
  for (int o = 128; o > 0; o >>= 1) { if (tid < o) red[tid] += red[tid + o]; __syncthreads(); }
  const float var_sum = red[0];
  __syncthreads();
  red[tid] = sa; __syncthreads();
#pragma unroll
  for (int o = 128; o > 0; o >>= 1) { if (tid < o) red[tid] += red[tid + o]; __syncthreads(); }
  const float abs_sum = red[0];
  const float stdv = sqrtf(var_sum / 2303.0f);       // unbiased (ddof=1)
  const float mean_abs = abs_sum / (2304.0f * stdv); // mean |bw|
  const float sw = exp2f(rintf(log2f(mean_abs)));    // half-even like jnp.round

  const int z = co >> 7, row = co & 127;
  const int wv = row >> 6, m = (row >> 4) & 3, l15w = row & 15;
#pragma unroll
  for (int j = 0; j < 9; ++j) {
    int i = tid + j * 256;        // i = cin*9 + tap  (OIHW flat)
    int cin = i / 9;
    int tap = i - cin * 9;
    float d = v[j] - mean;
    int8_t bits = (d > 0.f) ? (int8_t)1 : ((d < 0.f) ? (int8_t)-1 : (int8_t)0);
    // A-fragment order, palindrome cin-half schedule (h: 0,1,1,0):
    //   g = z*18 + (c0i ^ z)*9 + tap   -> [g][wv][m*2+kb][lane(64)][e(16)]
    int c0i = cin >> 7, cl = cin & 127;
    int chunk = cl >> 4;                 // 0..7 (16 cin each)
    int kb = chunk >> 2, chp = chunk & 3, e = cl & 15;
    int lane = chp * 16 + l15w;
    int g = z * 18 + ((c0i ^ z)) * 9 + tap;
    size_t flat = (size_t)(g * 2 + wv) * 8192
                + (m * 2 + kb) * 1024 + lane * 16 + e;
    wfrag[flat] = bits;
  }
  if (tid == 0) {
    float inv = gamma[co] / sqrtf(rvar[co] + 1e-5f);
    Sc[co] = sw * inv;
    Tc[co] = beta[co] - rmean[co] * inv;
  }
}

// ---------------- async global->LDS, 16B ----------------
__device__ __forceinline__ void gload_lds16(const void* g, void* l) {
  __builtin_amdgcn_global_load_lds(
      (const __attribute__((address_space(1))) uint32_t*)g,
      (__attribute__((address_space(3))) uint32_t*)l, 16, 0, 0);
}

// ---------------- binary conv as implicit GEMM (i8 MFMA) ----------------
// Block: one (tile,b) pair, BOTH co-halves; 4 waves, wave = 64co x 64px,
// acc[4][4] i32. X ONE 32KB cin-half, palindrome order (restage at s==9 per z).
// 36 steps (z=0: 18 + epilogue, z=1: 18 + epilogue); af confined per-z;
// bf per-kb. LDS 32KB + VGPR<=128 -> 4 blocks/CU.
__global__ __launch_bounds__(256, 2) void conv_kernel(
    const int8_t* __restrict__ xp, const int8_t* __restrict__ wfrag,
    const float* __restrict__ Sc, const float* __restrict__ Tc,
    float* __restrict__ out) {
  const int tile = blockIdx.x;           // 0..24
  const int b    = blockIdx.y;           // 0..31
  const int s0   = tile * 128;

  const int tid  = threadIdx.x;
  const int lane = tid & 63;
  const int wave = tid >> 6;
  const int wv   = wave >> 1;            // co 64-half within z-half
  const int wco  = wv * 64;
  const int wp   = (wave & 1) * 64;      // px 64-half
  const int l15  = lane & 15;
  const int chp  = lane >> 4;            // 16B k-chunk position 0..3

  __shared__ uint8_t XsF[XHALF];         // 32 KB: one cin-half, 128B rows, swizzled

  const int h0   = s0 / 56;
  const int base = s0 + 2 * h0;          // padded(s)=s+2h+59; base = padded(s0)-59

  int offn[4];
#pragma unroll
  for (int n = 0; n < 4; ++n) {
    int s = s0 + wp + n * 16 + l15;
    int sc = s < SPAT ? s : SPAT - 1;    // dummy px clamped (stores masked)
    int h = sc / 56;
    offn[n] = sc + 2 * h + 59 - base;    // in [59, 190]
  }

  const int8_t* xb  = xp + (size_t)b * SPAD * CIN;
  const int8_t* wba = wfrag + (size_t)wv * 8192 + (size_t)lane * 16;

  // stage one cin-half: 2048 16B chunks (256 rows x 8), source pre-swizzled
  auto issueX = [&](int c0e) {
#pragma unroll
    for (int j = 0; j < 8; ++j) {
      int q   = j * 256 + tid;
      int row = q >> 3, c = q & 7;
      int gr  = base + row;
      if (gr > SPAD - 1) gr = SPAD - 1;  // clamp: only feeds dummy px
      gload_lds16(xb + (size_t)gr * CIN + c0e + ((c ^ (row & 7)) << 4),
                  XsF + (q << 4));
    }
  };

  int4v af[2][8];                        // ping-pong prefetch (compiler-managed)
  auto loadAf = [&](int g, int buf) {    // g = 0..35 linear
#pragma unroll
    for (int q8 = 0; q8 < 8; ++q8)
      af[buf][q8] = *(const int4v*)(wba + (size_t)g * 16384 + q8 * 1024);
  };

  int4v acc[4][4];
#pragma unroll
  for (int m = 0; m < 4; ++m)
#pragma unroll
    for (int n = 0; n < 4; ++n) acc[m][n] = (int4v){0, 0, 0, 0};

  // prologue: X half0 + af(0); single full drain + barrier
  issueX(0);
  loadAf(0, 0);
  __syncthreads();                       // vmcnt(0)+lgkmcnt(0)+barrier: X resident

#pragma unroll 1
  for (int z = 0; z < 2; ++z) {
    if (z) loadAf(18, 0);                // cold reload once; af NOT live across epilogue

#pragma unroll
    for (int s = 0; s < 18; ++s) {
      const int cur = s & 1;
      const int tap = s < 9 ? s : s - 9;
      const int tapoff = (tap / 3) * 58 + (tap - (tap / 3) * 3) - 59;

      if (s == 9) {                      // palindrome restage: z=0 ->half1, z=1 ->half0
        asm volatile("s_waitcnt lgkmcnt(0)" ::: "memory");
        __builtin_amdgcn_s_barrier();    // everyone done reading current half
        issueX(z == 0 ? 128 : 0);
        asm volatile("s_waitcnt vmcnt(0)" ::: "memory");  // own DMA (+af) retired
        __builtin_amdgcn_s_barrier();    // all DMA landed
      }

      if (s < 17) loadAf(z * 18 + s + 1, cur ^ 1);  // prefetch within this z only

#pragma unroll
      for (int kb = 0; kb < 2; ++kb) {
        // bf per kb: 4 transient b128 reads, consumed immediately
        int4v bf[4];
#pragma unroll
        for (int n = 0; n < 4; ++n) {
          int r = offn[n] + tapoff;
          bf[n] = *(const int4v*)(XsF + (r << 7)
                                  + (((kb * 4 + chp) ^ (r & 7)) << 4));
        }
        __builtin_amdgcn_s_setprio(1);
#pragma unroll
        for (int m = 0; m < 4; ++m)
#pragma unroll
          for (int n = 0; n < 4; ++n)
            acc[m][n] = __builtin_amdgcn_mfma_i32_16x16x64_i8(
                af[cur][m * 2 + kb], bf[n], acc[m][n], 0, 0, 0);
        __builtin_amdgcn_s_setprio(0);
      }
    }

    // epilogue for this z-half: out = clip((float)acc * S + T), layout [b][co][s]
#pragma unroll
    for (int m = 0; m < 4; ++m) {
      const int cor0 = z * 128 + wco + m * 16 + chp * 4;
      float Sv[4], Tv[4];
#pragma unroll
      for (int r = 0; r < 4; ++r) { Sv[r] = Sc[cor0 + r]; Tv[r] = Tc[cor0 + r]; }
#pragma unroll
      for (int n = 0; n < 4; ++n) {
        const int s = s0 + wp + n * 16 + l15;
        if (s < SPAT) {
          float* op = out + ((size_t)b * COUT + cor0) * SPAT + s;
#pragma unroll
          for (int r = 0; r < 4; ++r) {
            float v = (float)acc[m][n][r] * Sv[r] + Tv[r];
            v = fminf(1.0f, fmaxf(-1.0f, v));
            op[(size_t)r * SPAT] = v;
          }
        }
      }
    }
    if (z == 0) {                        // re-zero acc for the second co-half
#pragma unroll
      for (int m = 0; m < 4; ++m)
#pragma unroll
        for (int n = 0; n < 4; ++n) acc[m][n] = (int4v){0, 0, 0, 0};
    }
  }
}

extern "C" void kernel_launch(void* const* d_in, const int* in_sizes, int n_in,
                              void* d_out, int out_size, void* d_ws, size_t ws_size,
                              hipStream_t stream) {
  const float* x     = (const float*)d_in[0];
  const float* wgt   = (const float*)d_in[1];
  const float* gamma = (const float*)d_in[2];
  const float* beta  = (const float*)d_in[3];
  const float* rmean = (const float*)d_in[4];
  const float* rvar  = (const float*)d_in[5];
  float* out = (float*)d_out;

  int8_t* xp = (int8_t*)d_ws;
  const size_t xp_bytes = (size_t)BATCH * SPAD * CIN;        // 27.6 MB
  int8_t* wfrag = xp + xp_bytes;
  const size_t wfrag_bytes = (size_t)2 * 294912;             // 590 KB
  float* Sc = (float*)(wfrag + wfrag_bytes);
  float* Tc = Sc + COUT;

  prep_kernel<<<dim3(58, BATCH), 256, 0, stream>>>(x, xp, wgt, gamma, beta,
                                                   rmean, rvar, wfrag, Sc, Tc);
  conv_kernel<<<dim3(25, BATCH), 256, 0, stream>>>(xp, wfrag, Sc, Tc, out);
}

// Round 18
// 98.113 us; speedup vs baseline: 1.1035x; 1.1035x over previous
//
#include <hip/hip_runtime.h>
#include <hip/hip_bf16.h>
#include <cstdint>
#include <cstddef>

// IR-Net binary conv 3x3 s1 p1 + BN(inference) + hardtanh, B=32 Cin=Cout=256 H=W=56.
// Ternary operands -> EXACT int8 MFMA implicit GEMM (mfma_i32_16x16x64_i8).
// R18 = R16's exact per-wave register body (acc[4][4], af ping-pong confined,
//   per-kb bf, no in-loop barriers) but in 512-thread / 8-wave blocks covering
//   256co x 128px in ONE pass (wv = wave>>1 spans all 4 co-quarters; no z loop).
//   LDS = 64KB X (both cin-halves, staged once) -> 2 blocks/CU x 8 waves =
//   16 waves/CU = 4 waves/SIMD: doubles the TLP hiding the per-step af drain
//   with identical per-wave code (R17 showed extra in-loop control flow = spill).

typedef int int4v __attribute__((ext_vector_type(4)));

#define CIN   256
#define COUT  256
#define SPAT  3136   // 56*56
#define SPAD  3364   // 58*58 padded spatial
#define BATCH 32
#define XHALF 32768  // 256 rows x 128 B

// ---------------- fused prep: pack X (sign->i8, padded), halo clear, W prep ----------------
__global__ __launch_bounds__(256) void prep_kernel(
    const float* __restrict__ x, int8_t* __restrict__ xp,
    const float* __restrict__ wgt, const float* __restrict__ gamma,
    const float* __restrict__ beta, const float* __restrict__ rmean,
    const float* __restrict__ rvar, int8_t* __restrict__ wfrag,
    float* __restrict__ Sc, float* __restrict__ Tc) {
  const int bx  = blockIdx.x;
  const int by  = blockIdx.y;
  const int tid = threadIdx.x;

  if (bx < 49) {                         // ---- pack: 64 px x 256 cin for image by
    const int s0 = bx * 64;
    __shared__ uint8_t xt[64][272];      // 64 px x 256 cin bytes (+16 pad)
    const int g  = tid >> 6;             // cin quarter 0..3
    const int si = tid & 63;             // px within chunk
#pragma unroll
    for (int k = 0; k < 4; ++k) {        // 16 cin per iter -> one 16B LDS store
      const int cin16 = (g * 4 + k) * 16;
      const float* src = x + ((size_t)by * CIN + cin16) * SPAT + s0 + si;
      uint32_t w[4] = {0u, 0u, 0u, 0u};
#pragma unroll
      for (int e = 0; e < 16; ++e) {
        float v = src[(size_t)e * SPAT];
        uint32_t sb = (v > 0.f) ? 1u : ((v < 0.f) ? 0xFFu : 0u);
        w[e >> 2] |= sb << ((e & 3) * 8);
      }
      *(int4v*)&xt[si][cin16] = (int4v){(int)w[0], (int)w[1], (int)w[2], (int)w[3]};
    }
    __syncthreads();
    const int row = tid >> 2;            // px 0..63
    const int sub = tid & 3;             // 64-cin quarter
    const int s = s0 + row;
    const int h = s / 56;
    int8_t* dst = xp + ((size_t)by * SPAD + (size_t)(s + 2 * h + 59)) * CIN + sub * 64;
#pragma unroll
    for (int j = 0; j < 4; ++j)
      *(int4v*)(dst + j * 16) = *(const int4v*)&xt[row][sub * 64 + j * 16];
    return;
  }

  if (bx == 49) {                        // ---- halo: zero 228 pad pixels of image by
    int8_t* xpb = xp + (size_t)by * SPAD * CIN;
    const int4v zz = (int4v){0, 0, 0, 0};
    for (int q = tid; q < 228 * 16; q += 256) {
      int p = q >> 4, c = q & 15;
      int pp;
      if (p < 58)       pp = p;                      // top row 0
      else if (p < 116) pp = 57 * 58 + (p - 58);     // bottom row 57
      else if (p < 172) pp = (p - 116 + 1) * 58;     // left col, rows 1..56
      else              pp = (p - 172 + 1) * 58 + 57;// right col, rows 1..56
      *(int4v*)(xpb + (size_t)pp * CIN + c * 16) = zz;
    }
    return;
  }

  // ---- W prep: co = (bx-50)*32 + by, one cout channel per block
  const int co = (bx - 50) * 32 + by;
  __shared__ float red[256];
  const float* wc = wgt + (size_t)co * 2304;
  float v[9];
#pragma unroll
  for (int j = 0; j < 9; ++j) v[j] = wc[tid + j * 256];
  float s = 0.f;
#pragma unroll
  for (int j = 0; j < 9; ++j) s += v[j];
  red[tid] = s; __syncthreads();
#pragma unroll
  for (int o = 128; o > 0; o >>= 1) { if (tid < o) red[tid] += red[tid + o]; __syncthreads(); }
  const float mean = red[0] * (1.0f / 2304.0f);
  __syncthreads();
  float ss = 0.f, sa = 0.f;
#pragma unroll
  for (int j = 0; j < 9; ++j) {
    float d = v[j] - mean;
    ss += d * d;
    sa += fabsf(d);
  }
  red[tid] = ss; __syncthreads();
#pragma unroll
  for (int o = 128; o > 0; o >>= 1) { if (tid < o) red[tid] += red[tid + o]; __syncthreads(); }
  const float var_sum = red[0];
  __syncthreads();
  red[tid] = sa; __syncthreads();
#pragma unroll
  for (int o = 128; o > 0; o >>= 1) { if (tid < o) red[tid] += red[tid + o]; __syncthreads(); }
  const float abs_sum = red[0];
  const float stdv = sqrtf(var_sum / 2303.0f);       // unbiased (ddof=1)
  const float mean_abs = abs_sum / (2304.0f * stdv); // mean |bw|
  const float sw = exp2f(rintf(log2f(mean_abs)));    // half-even like jnp.round

  // co decomposition for 8-wave blocks: wv = co>>6 (quarter), m = (co>>4)&3
  const int wv = co >> 6, m = (co >> 4) & 3, l15w = co & 15;
#pragma unroll
  for (int j = 0; j < 9; ++j) {
    int i = tid + j * 256;        // i = cin*9 + tap  (OIHW flat)
    int cin = i / 9;
    int tap = i - cin * 9;
    float d = v[j] - mean;
    int8_t bits = (d > 0.f) ? (int8_t)1 : ((d < 0.f) ? (int8_t)-1 : (int8_t)0);
    // A-fragment order: [g=c0i*9+tap][wv(4)][m*2+kb][lane(64)][e(16)]
    int c0i = cin >> 7, cl = cin & 127;
    int chunk = cl >> 4;                 // 0..7 (16 cin each)
    int kb = chunk >> 2, chp = chunk & 3, e = cl & 15;
    int lane = chp * 16 + l15w;
    int g = c0i * 9 + tap;
    size_t flat = ((size_t)(g * 4 + wv) * 8 + (m * 2 + kb)) * 1024 + lane * 16 + e;
    wfrag[flat] = bits;
  }
  if (tid == 0) {
    float inv = gamma[co] / sqrtf(rvar[co] + 1e-5f);
    Sc[co] = sw * inv;
    Tc[co] = beta[co] - rmean[co] * inv;
  }
}

// ---------------- async global->LDS, 16B ----------------
__device__ __forceinline__ void gload_lds16(const void* g, void* l) {
  __builtin_amdgcn_global_load_lds(
      (const __attribute__((address_space(1))) uint32_t*)g,
      (__attribute__((address_space(3))) uint32_t*)l, 16, 0, 0);
}

// ---------------- binary conv as implicit GEMM (i8 MFMA) ----------------
// Block: 512 threads / 8 waves, 256co x 128px, one (tile,b) pair, single pass.
// wave = 64co x 64px (wv = wave>>1 co-quarter, wp = (wave&1) px-half), acc[4][4].
// X both cin-halves staged once (64KB); 18 steps, no in-loop barriers.
__global__ __launch_bounds__(512, 2) void conv_kernel(
    const int8_t* __restrict__ xp, const int8_t* __restrict__ wfrag,
    const float* __restrict__ Sc, const float* __restrict__ Tc,
    float* __restrict__ out) {
  const int tile = blockIdx.x;           // 0..24
  const int b    = blockIdx.y;           // 0..31
  const int s0   = tile * 128;

  const int tid  = threadIdx.x;
  const int lane = tid & 63;
  const int wave = tid >> 6;             // 0..7
  const int wv   = wave >> 1;            // co quarter 0..3
  const int wp   = (wave & 1) * 64;      // px half
  const int l15  = lane & 15;
  const int chp  = lane >> 4;            // 16B k-chunk position 0..3

  __shared__ uint8_t XsF[2 * XHALF];     // 64 KB: both cin-halves, 128B rows, swizzled

  const int h0   = s0 / 56;
  const int base = s0 + 2 * h0;          // padded(s)=s+2h+59; base = padded(s0)-59

  int offn[4];
#pragma unroll
  for (int n = 0; n < 4; ++n) {
    int s = s0 + wp + n * 16 + l15;
    int sc = s < SPAT ? s : SPAT - 1;    // dummy px clamped (stores masked)
    int h = sc / 56;
    offn[n] = sc + 2 * h + 59 - base;    // in [59, 190]
  }

  const int8_t* xb  = xp + (size_t)b * SPAD * CIN;
  const int8_t* wba = wfrag + (size_t)wv * 8192 + (size_t)lane * 16;

  // stage both cin-halves: 4096 16B chunks, 8 per thread, source pre-swizzled
  auto issueX = [&]() {
#pragma unroll
    for (int j = 0; j < 8; ++j) {
      int q   = j * 512 + tid;           // 0..4095
      int hf  = q >> 11;                 // cin-half
      int qq  = q & 2047;
      int row = qq >> 3, c = qq & 7;
      int gr  = base + row;
      if (gr > SPAD - 1) gr = SPAD - 1;  // clamp: only feeds dummy px
      gload_lds16(xb + (size_t)gr * CIN + hf * 128 + ((c ^ (row & 7)) << 4),
                  XsF + ((size_t)q << 4));
    }
  };

  int4v af[2][8];                        // ping-pong prefetch (compiler-managed)
  auto loadAf = [&](int g, int buf) {    // g = 0..17
#pragma unroll
    for (int q8 = 0; q8 < 8; ++q8)
      af[buf][q8] = *(const int4v*)(wba + (size_t)g * 32768 + q8 * 1024);
  };

  int4v acc[4][4];
#pragma unroll
  for (int m = 0; m < 4; ++m)
#pragma unroll
    for (int n = 0; n < 4; ++n) acc[m][n] = (int4v){0, 0, 0, 0};

  // prologue: both X halves + af(0); single full drain + barrier (once per block)
  issueX();
  loadAf(0, 0);
  __syncthreads();                       // vmcnt(0)+lgkmcnt(0)+barrier: X resident

#pragma unroll
  for (int s = 0; s < 18; ++s) {
    const int cur = s & 1;
    const int tap = s < 9 ? s : s - 9;
    const int tapoff = (tap / 3) * 58 + (tap - (tap / 3) * 3) - 59;
    const int hof = (s >= 9) ? XHALF : 0;

    if (s < 17) loadAf(s + 1, cur ^ 1);  // prefetch next step

#pragma unroll
    for (int kb = 0; kb < 2; ++kb) {
      // bf per kb: 4 transient b128 reads, consumed immediately
      int4v bf[4];
#pragma unroll
      for (int n = 0; n < 4; ++n) {
        int r = offn[n] + tapoff;
        bf[n] = *(const int4v*)(XsF + hof + (r << 7)
                                + (((kb * 4 + chp) ^ (r & 7)) << 4));
      }
      __builtin_amdgcn_s_setprio(1);
#pragma unroll
      for (int m = 0; m < 4; ++m)
#pragma unroll
        for (int n = 0; n < 4; ++n)
          acc[m][n] = __builtin_amdgcn_mfma_i32_16x16x64_i8(
              af[cur][m * 2 + kb], bf[n], acc[m][n], 0, 0, 0);
      __builtin_amdgcn_s_setprio(0);
    }
  }

  // epilogue: out = clip((float)acc * S + T), layout [b][co][s]
#pragma unroll
  for (int m = 0; m < 4; ++m) {
    const int cor0 = wv * 64 + m * 16 + chp * 4;
    float Sv[4], Tv[4];
#pragma unroll
    for (int r = 0; r < 4; ++r) { Sv[r] = Sc[cor0 + r]; Tv[r] = Tc[cor0 + r]; }
#pragma unroll
    for (int n = 0; n < 4; ++n) {
      const int s = s0 + wp + n * 16 + l15;
      if (s < SPAT) {
        float* op = out + ((size_t)b * COUT + cor0) * SPAT + s;
#pragma unroll
        for (int r = 0; r < 4; ++r) {
          float v = (float)acc[m][n][r] * Sv[r] + Tv[r];
          v = fminf(1.0f, fmaxf(-1.0f, v));
          op[(size_t)r * SPAT] = v;
        }
      }
    }
  }
}

extern "C" void kernel_launch(void* const* d_in, const int* in_sizes, int n_in,
                              void* d_out, int out_size, void* d_ws, size_t ws_size,
                              hipStream_t stream) {
  const float* x     = (const float*)d_in[0];
  const float* wgt   = (const float*)d_in[1];
  const float* gamma = (const float*)d_in[2];
  const float* beta  = (const float*)d_in[3];
  const float* rmean = (const float*)d_in[4];
  const float* rvar  = (const float*)d_in[5];
  float* out = (float*)d_out;

  int8_t* xp = (int8_t*)d_ws;
  const size_t xp_bytes = (size_t)BATCH * SPAD * CIN;        // 27.6 MB
  int8_t* wfrag = xp + xp_bytes;
  const size_t wfrag_bytes = (size_t)18 * 4 * 8192;          // 590 KB
  float* Sc = (float*)(wfrag + wfrag_bytes);
  float* Tc = Sc + COUT;

  prep_kernel<<<dim3(58, BATCH), 256, 0, stream>>>(x, xp, wgt, gamma, beta,
                                                   rmean, rvar, wfrag, Sc, Tc);
  conv_kernel<<<dim3(25, BATCH), 512, 0, stream>>>(xp, wfrag, Sc, Tc, out);
}

// Round 19
// 92.574 us; speedup vs baseline: 1.1695x; 1.0598x over previous
//
#include <hip/hip_runtime.h>
#include <hip/hip_bf16.h>
#include <cstdint>
#include <cstddef>

// IR-Net binary conv 3x3 s1 p1 + BN(inference) + hardtanh, B=32 Cin=Cout=256 H=W=56.
// Ternary operands -> EXACT int8 MFMA implicit GEMM (mfma_i32_16x16x64_i8).
// R19 = R16 verbatim (the measured champion: 92.8us total, conv 71.4us).
//   Structure: z-merge (both co-halves per block, X staged once in 64KB LDS),
//   zero in-loop barriers, af ping-pong confined per-z, per-kb bf (no spill,
//   VGPR 116), fused pack/halo/W-prep. R17 (mid-loop restage) and R18 (8-wave)
//   both regressed; serial-sum analysis shows remaining gains need asm-level
//   interleave control not expressible in HIP source.

typedef int int4v __attribute__((ext_vector_type(4)));

#define CIN   256
#define COUT  256
#define SPAT  3136   // 56*56
#define SPAD  3364   // 58*58 padded spatial
#define BATCH 32
#define XHALF 32768  // 256 rows x 128 B

// ---------------- fused prep: pack X (sign->i8, padded), halo clear, W prep ----------------
__global__ __launch_bounds__(256) void prep_kernel(
    const float* __restrict__ x, int8_t* __restrict__ xp,
    const float* __restrict__ wgt, const float* __restrict__ gamma,
    const float* __restrict__ beta, const float* __restrict__ rmean,
    const float* __restrict__ rvar, int8_t* __restrict__ wfrag,
    float* __restrict__ Sc, float* __restrict__ Tc) {
  const int bx  = blockIdx.x;
  const int by  = blockIdx.y;
  const int tid = threadIdx.x;

  if (bx < 49) {                         // ---- pack: 64 px x 256 cin for image by
    const int s0 = bx * 64;
    __shared__ uint8_t xt[64][272];      // 64 px x 256 cin bytes (+16 pad)
    const int g  = tid >> 6;             // cin quarter 0..3
    const int si = tid & 63;             // px within chunk
#pragma unroll
    for (int k = 0; k < 4; ++k) {        // 16 cin per iter -> one 16B LDS store
      const int cin16 = (g * 4 + k) * 16;
      const float* src = x + ((size_t)by * CIN + cin16) * SPAT + s0 + si;
      uint32_t w[4] = {0u, 0u, 0u, 0u};
#pragma unroll
      for (int e = 0; e < 16; ++e) {
        float v = src[(size_t)e * SPAT];
        uint32_t sb = (v > 0.f) ? 1u : ((v < 0.f) ? 0xFFu : 0u);
        w[e >> 2] |= sb << ((e & 3) * 8);
      }
      *(int4v*)&xt[si][cin16] = (int4v){(int)w[0], (int)w[1], (int)w[2], (int)w[3]};
    }
    __syncthreads();
    const int row = tid >> 2;            // px 0..63
    const int sub = tid & 3;             // 64-cin quarter
    const int s = s0 + row;
    const int h = s / 56;
    int8_t* dst = xp + ((size_t)by * SPAD + (size_t)(s + 2 * h + 59)) * CIN + sub * 64;
#pragma unroll
    for (int j = 0; j < 4; ++j)
      *(int4v*)(dst + j * 16) = *(const int4v*)&xt[row][sub * 64 + j * 16];
    return;
  }

  if (bx == 49) {                        // ---- halo: zero 228 pad pixels of image by
    int8_t* xpb = xp + (size_t)by * SPAD * CIN;
    const int4v zz = (int4v){0, 0, 0, 0};
    for (int q = tid; q < 228 * 16; q += 256) {
      int p = q >> 4, c = q & 15;
      int pp;
      if (p < 58)       pp = p;                      // top row 0
      else if (p < 116) pp = 57 * 58 + (p - 58);     // bottom row 57
      else if (p < 172) pp = (p - 116 + 1) * 58;     // left col, rows 1..56
      else              pp = (p - 172 + 1) * 58 + 57;// right col, rows 1..56
      *(int4v*)(xpb + (size_t)pp * CIN + c * 16) = zz;
    }
    return;
  }

  // ---- W prep: co = (bx-50)*32 + by, one cout channel per block
  const int co = (bx - 50) * 32 + by;
  __shared__ float red[256];
  const float* wc = wgt + (size_t)co * 2304;
  float v[9];
#pragma unroll
  for (int j = 0; j < 9; ++j) v[j] = wc[tid + j * 256];
  float s = 0.f;
#pragma unroll
  for (int j = 0; j < 9; ++j) s += v[j];
  red[tid] = s; __syncthreads();
#pragma unroll
  for (int o = 128; o > 0; o >>= 1) { if (tid < o) red[tid] += red[tid + o]; __syncthreads(); }
  const float mean = red[0] * (1.0f / 2304.0f);
  __syncthreads();
  float ss = 0.f, sa = 0.f;
#pragma unroll
  for (int j = 0; j < 9; ++j) {
    float d = v[j] - mean;
    ss += d * d;
    sa += fabsf(d);
  }
  red[tid] = ss; __syncthreads();
#pragma unroll
  for (int o = 128; o > 0; o >>= 1) { if (tid < o) red[tid] += red[tid + o]; __syncthreads(); }
  const float var_sum = red[0];
  __syncthreads();
  red[tid] = sa; __syncthreads();
#pragma unroll
  for (int o = 128; o > 0; o >>= 1) { if (tid < o) red[tid] += red[tid + o]; __syncthreads(); }
  const float abs_sum = red[0];
  const float stdv = sqrtf(var_sum / 2303.0f);       // unbiased (ddof=1)
  const float mean_abs = abs_sum / (2304.0f * stdv); // mean |bw|
  const float sw = exp2f(rintf(log2f(mean_abs)));    // half-even like jnp.round

  const int z = co >> 7, row = co & 127;
  const int wv = row >> 6, m = (row >> 4) & 3, l15w = row & 15;
#pragma unroll
  for (int j = 0; j < 9; ++j) {
    int i = tid + j * 256;        // i = cin*9 + tap  (OIHW flat)
    int cin = i / 9;
    int tap = i - cin * 9;
    float d = v[j] - mean;
    int8_t bits = (d > 0.f) ? (int8_t)1 : ((d < 0.f) ? (int8_t)-1 : (int8_t)0);
    // A-fragment order: [g=z*18+c0i*9+tap][wv][m*2+kb][lane(64)][e(16)]
    int c0i = cin >> 7, cl = cin & 127;
    int chunk = cl >> 4;                 // 0..7 (16 cin each)
    int kb = chunk >> 2, chp = chunk & 3, e = cl & 15;
    int lane = chp * 16 + l15w;
    int g = z * 18 + c0i * 9 + tap;
    size_t flat = (size_t)(g * 2 + wv) * 8192
                + (m * 2 + kb) * 1024 + lane * 16 + e;
    wfrag[flat] = bits;
  }
  if (tid == 0) {
    float inv = gamma[co] / sqrtf(rvar[co] + 1e-5f);
    Sc[co] = sw * inv;
    Tc[co] = beta[co] - rmean[co] * inv;
  }
}

// ---------------- async global->LDS, 16B ----------------
__device__ __forceinline__ void gload_lds16(const void* g, void* l) {
  __builtin_amdgcn_global_load_lds(
      (const __attribute__((address_space(1))) uint32_t*)g,
      (__attribute__((address_space(3))) uint32_t*)l, 16, 0, 0);
}

// ---------------- binary conv as implicit GEMM (i8 MFMA) ----------------
// Block: one (tile,b) pair, BOTH co-halves; 4 waves, wave = 64co x 64px,
// acc[4][4] i32. X both cin-halves staged once (64KB); 36 steps
// (z=0: 18 + epilogue, z=1: 18 + epilogue), no in-loop barriers.
// af prefetch confined per-z; bf loaded PER-KB (16 transient regs).
__global__ __launch_bounds__(256, 2) void conv_kernel(
    const int8_t* __restrict__ xp, const int8_t* __restrict__ wfrag,
    const float* __restrict__ Sc, const float* __restrict__ Tc,
    float* __restrict__ out) {
  const int tile = blockIdx.x;           // 0..24
  const int b    = blockIdx.y;           // 0..31
  const int s0   = tile * 128;

  const int tid  = threadIdx.x;
  const int lane = tid & 63;
  const int wave = tid >> 6;
  const int wv   = wave >> 1;            // co 64-half within z-half
  const int wco  = wv * 64;
  const int wp   = (wave & 1) * 64;      // px 64-half
  const int l15  = lane & 15;
  const int chp  = lane >> 4;            // 16B k-chunk position 0..3

  __shared__ uint8_t XsF[2 * XHALF];     // 64 KB: both cin-halves, 128B rows, swizzled

  const int h0   = s0 / 56;
  const int base = s0 + 2 * h0;          // padded(s)=s+2h+59; base = padded(s0)-59

  int offn[4];
#pragma unroll
  for (int n = 0; n < 4; ++n) {
    int s = s0 + wp + n * 16 + l15;
    int sc = s < SPAT ? s : SPAT - 1;    // dummy px clamped (stores masked)
    int h = sc / 56;
    offn[n] = sc + 2 * h + 59 - base;    // in [59, 190]
  }

  const int8_t* xb  = xp + (size_t)b * SPAD * CIN;
  const int8_t* wba = wfrag + (size_t)wv * 8192 + (size_t)lane * 16;

  // stage one cin-half: 2048 16B chunks (256 rows x 8), source pre-swizzled
  auto issueX = [&](int bufi, int c0e) {
#pragma unroll
    for (int j = 0; j < 8; ++j) {
      int q   = j * 256 + tid;
      int row = q >> 3, c = q & 7;
      int gr  = base + row;
      if (gr > SPAD - 1) gr = SPAD - 1;  // clamp: only feeds dummy px
      gload_lds16(xb + (size_t)gr * CIN + c0e + ((c ^ (row & 7)) << 4),
                  XsF + bufi * XHALF + (q << 4));
    }
  };

  int4v af[2][8];                        // ping-pong prefetch (compiler-managed)
  auto loadAf = [&](int g, int buf) {    // g = 0..35 linear (z stride = 18 steps)
#pragma unroll
    for (int q8 = 0; q8 < 8; ++q8)
      af[buf][q8] = *(const int4v*)(wba + (size_t)g * 16384 + q8 * 1024);
  };

  int4v acc[4][4];
#pragma unroll
  for (int m = 0; m < 4; ++m)
#pragma unroll
    for (int n = 0; n < 4; ++n) acc[m][n] = (int4v){0, 0, 0, 0};

  // prologue: both X halves + af(0); single full drain + barrier (once per block)
  issueX(0, 0);
  issueX(1, 128);
  loadAf(0, 0);
  __syncthreads();                       // vmcnt(0)+lgkmcnt(0)+barrier: X resident

#pragma unroll 1
  for (int z = 0; z < 2; ++z) {
    if (z) loadAf(18, 0);                // cold reload once; af NOT live across epilogue

#pragma unroll
    for (int s = 0; s < 18; ++s) {
      const int cur = s & 1;
      const int tap = s < 9 ? s : s - 9;
      const int tapoff = (tap / 3) * 58 + (tap - (tap / 3) * 3) - 59;
      const int hof = (s >= 9) ? XHALF : 0;

      if (s < 17) loadAf(z * 18 + s + 1, cur ^ 1);  // prefetch within this z only

#pragma unroll
      for (int kb = 0; kb < 2; ++kb) {
        // bf per kb: 4 transient b128 reads, consumed immediately
        int4v bf[4];
#pragma unroll
        for (int n = 0; n < 4; ++n) {
          int r = offn[n] + tapoff;
          bf[n] = *(const int4v*)(XsF + hof + (r << 7)
                                  + (((kb * 4 + chp) ^ (r & 7)) << 4));
        }
        __builtin_amdgcn_s_setprio(1);
#pragma unroll
        for (int m = 0; m < 4; ++m)
#pragma unroll
          for (int n = 0; n < 4; ++n)
            acc[m][n] = __builtin_amdgcn_mfma_i32_16x16x64_i8(
                af[cur][m * 2 + kb], bf[n], acc[m][n], 0, 0, 0);
        __builtin_amdgcn_s_setprio(0);
      }
    }

    // epilogue for this z-half: out = clip((float)acc * S + T), layout [b][co][s]
#pragma unroll
    for (int m = 0; m < 4; ++m) {
      const int cor0 = z * 128 + wco + m * 16 + chp * 4;
      float Sv[4], Tv[4];
#pragma unroll
      for (int r = 0; r < 4; ++r) { Sv[r] = Sc[cor0 + r]; Tv[r] = Tc[cor0 + r]; }
#pragma unroll
      for (int n = 0; n < 4; ++n) {
        const int s = s0 + wp + n * 16 + l15;
        if (s < SPAT) {
          float* op = out + ((size_t)b * COUT + cor0) * SPAT + s;
#pragma unroll
          for (int r = 0; r < 4; ++r) {
            float v = (float)acc[m][n][r] * Sv[r] + Tv[r];
            v = fminf(1.0f, fmaxf(-1.0f, v));
            op[(size_t)r * SPAT] = v;
          }
        }
      }
    }
    if (z == 0) {                        // re-zero acc for the second co-half
#pragma unroll
      for (int m = 0; m < 4; ++m)
#pragma unroll
        for (int n = 0; n < 4; ++n) acc[m][n] = (int4v){0, 0, 0, 0};
    }
  }
}

extern "C" void kernel_launch(void* const* d_in, const int* in_sizes, int n_in,
                              void* d_out, int out_size, void* d_ws, size_t ws_size,
                              hipStream_t stream) {
  const float* x     = (const float*)d_in[0];
  const float* wgt   = (const float*)d_in[1];
  const float* gamma = (const float*)d_in[2];
  const float* beta  = (const float*)d_in[3];
  const float* rmean = (const float*)d_in[4];
  const float* rvar  = (const float*)d_in[5];
  float* out = (float*)d_out;

  int8_t* xp = (int8_t*)d_ws;
  const size_t xp_bytes = (size_t)BATCH * SPAD * CIN;        // 27.6 MB
  int8_t* wfrag = xp + xp_bytes;
  const size_t wfrag_bytes = (size_t)2 * 294912;             // 590 KB
  float* Sc = (float*)(wfrag + wfrag_bytes);
  float* Tc = Sc + COUT;

  prep_kernel<<<dim3(58, BATCH), 256, 0, stream>>>(x, xp, wgt, gamma, beta,
                                                   rmean, rvar, wfrag, Sc, Tc);
  conv_kernel<<<dim3(25, BATCH), 256, 0, stream>>>(xp, wfrag, Sc, Tc, out);
}